// Round 11
// baseline (367.552 us; speedup 1.0000x reference)
//
#include <hip/hip_runtime.h>
#include <hip/hip_bf16.h>

typedef unsigned short ushort_t;
typedef __attribute__((ext_vector_type(8))) short short8;
typedef __attribute__((ext_vector_type(4))) float floatx4;
typedef __attribute__((ext_vector_type(16))) float floatx16;

#define LOG2E 1.4426950408889634f

__device__ __forceinline__ unsigned short f2bf(float f) {
    unsigned u = __float_as_uint(f);
    u += 0x7FFF + ((u >> 16) & 1);   // RNE
    return (unsigned short)(u >> 16);
}

__device__ __forceinline__ void async_ld16(const void* gptr, void* lptr) {
    typedef const __attribute__((address_space(1))) unsigned int TG;
    typedef __attribute__((address_space(3))) unsigned int TL;
    __builtin_amdgcn_global_load_lds((TG*)(unsigned long long)gptr,
                                     (TL*)(unsigned)(unsigned long long)lptr,
                                     16, 0, 0);
}

// ---------------- fused prep: x->bf16 | w_qkv transpose | w_proj transpose ----------------
__global__ __launch_bounds__(256) void prep_kernel(const float* __restrict__ x,
                                                   const float* __restrict__ wqkv,
                                                   const float* __restrict__ wproj,
                                                   ushort_t* __restrict__ xb,
                                                   ushort_t* __restrict__ wqkvT,
                                                   ushort_t* __restrict__ wprojT) {
    __shared__ float t[32][33];
    int bx = blockIdx.x;
    if (bx < 8192) {
        int i = bx * 256 + threadIdx.x;
        float4 v = ((const float4*)x)[i];
        unsigned long long r = (unsigned long long)f2bf(v.x)
                             | ((unsigned long long)f2bf(v.y) << 16)
                             | ((unsigned long long)f2bf(v.z) << 32)
                             | ((unsigned long long)f2bf(v.w) << 48);
        ((unsigned long long*)xb)[i] = r;
        return;
    }
    const float* in; ushort_t* out; int R, C, bidx;
    if (bx < 8192 + 3072) { in = wqkv; out = wqkvT; R = 1024; C = 3072; bidx = bx - 8192; }
    else                  { in = wproj; out = wprojT; R = 1024; C = 1024; bidx = bx - 11264; }
    int nbc = C >> 5;
    int bc = bidx % nbc, br = bidx / nbc;
    int tx = threadIdx.x & 31, ty = threadIdx.x >> 5;   // 32 x 8
    int r0 = br << 5, c0 = bc << 5;
#pragma unroll
    for (int j = 0; j < 4; ++j)
        t[ty + j * 8][tx] = in[(size_t)(r0 + ty + j * 8) * C + c0 + tx];
    __syncthreads();
#pragma unroll
    for (int j = 0; j < 4; ++j)
        out[(size_t)(c0 + ty + j * 8) * R + r0 + tx] = f2bf(t[tx][ty + j * 8]);
}

// ---------------- QKV GEMM: 128x384 tile, BK=64, counted-vmcnt, 16 waves, zero tail -------
// (unchanged)
__global__ __launch_bounds__(1024) void gemm_qkv_kernel(const ushort_t* __restrict__ A,
                                                        const ushort_t* __restrict__ Bt,
                                                        const float* __restrict__ bias,
                                                        ushort_t* __restrict__ qbuf,
                                                        ushort_t* __restrict__ kbuf,
                                                        ushort_t* __restrict__ vtbuf) {
    extern __shared__ __align__(16) ushort_t lds[];

    int bid = blockIdx.x;
    int wg = (bid & 7) * 64 + (bid >> 3);      // XCD-bijective swizzle (512 % 8 == 0)
    int bm = wg & 63, bn = wg >> 6;            // 64 x 8
    int m0 = bm << 7, n0 = bn * 384;

    int tid = threadIdx.x;
    int wave = tid >> 6, lane = tid & 63;
    int c = lane & 15, g = lane >> 4;
    int wm = wave >> 3, wn = wave & 7;

    int row0 = tid >> 3;
    int sch  = (tid & 7) ^ (row0 & 7);
    size_t aoff = (size_t)(m0 + row0) * 1024 + sch * 8;
    size_t boff = (size_t)(n0 + row0) * 1024 + sch * 8;

    int co0 = (g * 8) ^ ((c & 7) << 3);
    int co1 = co0 ^ 32;

    floatx4 acc[4][3];
    short8 a[4][2], bb[2];
#pragma unroll
    for (int i2 = 0; i2 < 4; ++i2)
#pragma unroll
        for (int j2 = 0; j2 < 3; ++j2) { floatx4 z = {0.f,0.f,0.f,0.f}; acc[i2][j2] = z; }

    auto stA = [&](int t, int buf) {
        async_ld16(A + aoff + (size_t)t * 64, lds + buf * 8192 + tid * 8);
    };
    auto stB = [&](int t, int buf) {
        const ushort_t* s = Bt + boff + (size_t)t * 64;
        ushort_t* d = lds + 16384 + buf * 24576 + tid * 8;
        async_ld16(s, d);
        async_ld16(s + 131072, d + 8192);
        async_ld16(s + 262144, d + 16384);
    };
    auto ld_a = [&](int buf) {
#pragma unroll
        for (int mi = 0; mi < 4; ++mi) {
            int ro = buf * 8192 + (wm * 64 + mi * 16 + c) * 64;
            a[mi][0] = *(const short8*)&lds[ro + co0];
            a[mi][1] = *(const short8*)&lds[ro + co1];
        }
    };
    auto ld_b = [&](int buf, int nii) {
        int ro = 16384 + buf * 24576 + (wn * 48 + nii * 16 + c) * 64;
        bb[0] = *(const short8*)&lds[ro + co0];
        bb[1] = *(const short8*)&lds[ro + co1];
    };
    auto mm = [&](int nii) {
        asm volatile("s_barrier" ::: "memory");
        asm volatile("s_waitcnt lgkmcnt(0)" ::: "memory");
        __builtin_amdgcn_s_setprio(1);
#pragma unroll
        for (int mi = 0; mi < 4; ++mi)
#pragma unroll
            for (int ks = 0; ks < 2; ++ks)
                acc[mi][nii] = __builtin_amdgcn_mfma_f32_16x16x32_bf16(
                    a[mi][ks], bb[ks], acc[mi][nii], 0, 0, 0);
        __builtin_amdgcn_s_setprio(0);
        asm volatile("s_barrier" ::: "memory");
    };

    stA(0, 0); stB(0, 0);
    stA(1, 1); stB(1, 1);
    asm volatile("s_waitcnt vmcnt(4)" ::: "memory");
    asm volatile("s_barrier" ::: "memory");

#pragma unroll 1
    for (int t = 0; t < 14; ++t) {
        int buf = t & 1;
        ld_a(buf); ld_b(buf, 0);
        mm(0);
        ld_b(buf, 1);
        mm(1);
        ld_b(buf, 2);
        stA(t + 2, buf); stB(t + 2, buf);
        asm volatile("s_waitcnt vmcnt(4)" ::: "memory");
        mm(2);
    }
    ld_a(0); ld_b(0, 0);
    mm(0);
    ld_b(0, 1);
    mm(1);
    ld_b(0, 2);
    asm volatile("s_waitcnt vmcnt(0)" ::: "memory");
    mm(2);
    ld_a(1); ld_b(1, 0);
    mm(0);
    ld_b(1, 1);
    mm(1);
    ld_b(1, 2);
    mm(2);

    int b = m0 >> 11, sbase = m0 & 2047;
    float bv[3], scl[3];
    int headf[3], cinh[3], secf[3];
#pragma unroll
    for (int nii = 0; nii < 3; ++nii) {
        int cb = wn * 48 + nii * 16;
        bv[nii]   = bias[n0 + cb + c];
        headf[nii] = cb >> 6;
        cinh[nii]  = (cb & 63) + c;
        secf[nii]  = (n0 + cb) >> 10;
        scl[nii]   = (secf[nii] == 0) ? (0.125f * LOG2E) : 1.0f;
    }

    __syncthreads();

#pragma unroll
    for (int nii = 0; nii < 3; ++nii) {
        if (secf[nii] < 2) {
#pragma unroll
            for (int mi = 0; mi < 4; ++mi)
#pragma unroll
                for (int r = 0; r < 4; ++r) {
                    int row = wm * 64 + mi * 16 + g * 4 + r;
                    lds[headf[nii] * 9216 + row * 72 + cinh[nii]] =
                        f2bf((acc[mi][nii][r] + bv[nii]) * scl[nii]);
                }
        } else {
#pragma unroll
            for (int mi = 0; mi < 4; ++mi) {
                int d = cinh[nii];
                int s0 = wm * 64 + mi * 16 + g * 4;
                unsigned long long pk =
                      (unsigned long long)f2bf(acc[mi][nii][0] + bv[nii])
                    | ((unsigned long long)f2bf(acc[mi][nii][1] + bv[nii]) << 16)
                    | ((unsigned long long)f2bf(acc[mi][nii][2] + bv[nii]) << 32)
                    | ((unsigned long long)f2bf(acc[mi][nii][3] + bv[nii]) << 48);
                *(unsigned long long*)&lds[headf[nii] * 9216 + d * 136 + s0] = pk;
            }
        }
    }
    __syncthreads();

#pragma unroll 1
    for (int hl = 0; hl < 6; ++hl) {
        int colg = n0 + hl * 64;
        int sech = colg >> 10;
        int hg = (colg & 1023) >> 6;
        size_t bh = (size_t)(b * 16 + hg);
        if (sech < 2) {
            int row = tid >> 3, ch = tid & 7;
            ushort_t* dst = (sech == 0 ? qbuf : kbuf) + bh * 131072
                          + (size_t)(sbase + row) * 64 + ch * 8;
            *(short8*)dst = *(const short8*)&lds[hl * 9216 + row * 72 + ch * 8];
        } else {
            int d = tid >> 4, sq = tid & 15;
            ushort_t* dst = vtbuf + bh * 131072 + (size_t)d * 2048 + sbase + sq * 8;
            *(short8*)dst = *(const short8*)&lds[hl * 9216 + d * 136 + sq * 8];
        }
    }
}

// ---------------- flash attention: 32x32 MFMA, equal-work paired q-tiles ----------------
// R10 post-mortem: 17.4KB LDS made ALL 2048 blocks co-resident -> LPT queue empty ->
// same-length blocks clustered per CU -> 2.4x imbalance (R2 lesson repeated). Fix: make
// work per block CONSTANT. Each block processes the complementary q-tile pair
// (qb, 31-qb): kt-count = (qb+1)+(32-qb) = 33 for every block. Grid 1024 = exactly
// 4 blocks/CU, all resident, balanced under ANY block->CU mapping. Kernel body is R10's
// (passed, no spill) wrapped in a 2-pass loop; kt-loop-top barrier orders pass-1 Lo reads
// before pass-2 K/V staging (overlay safety unchanged).
__global__ __launch_bounds__(256, 4) void attn_kernel(const ushort_t* __restrict__ qb_,
                                                      const ushort_t* __restrict__ kb_,
                                                      const ushort_t* __restrict__ vtb_,
                                                      ushort_t* __restrict__ aout) {
    __shared__ __align__(16) ushort_t KV[8704];   // Ks @0 [64][68] | Vs @4352 [64][68]
    ushort_t* Ks = KV;
    ushort_t* Vs = KV + 4352;
    int bx = blockIdx.x;                // 1024 blocks
    int pair = bx >> 6;                 // 0..15
    int bhix = bx & 63;
    int b = bhix >> 4, h = bhix & 15;
    int tid = threadIdx.x, wave = tid >> 6, lane = tid & 63;
    int qh = wave >> 1, kh = wave & 1;
    int l31 = lane & 31, hi = lane >> 5;
    size_t bh = (size_t)(b * 16 + h);

    const ushort_t* Kp = kb_ + bh * 131072;
    const ushort_t* Vp = vtb_ + bh * 131072;

    short8 vones;
#pragma unroll
    for (int j = 0; j < 8; ++j) vones[j] = (short)0x3F80;   // bf16 1.0

#pragma unroll 1
    for (int pass = 0; pass < 2; ++pass) {
        int qb = pass ? (31 - pair) : pair;
        int q0 = qb << 6;

        const ushort_t* Qp = qb_ + (bh * 2048 + q0 + qh * 32 + l31) * 64;
        short8 qf[4];
#pragma unroll
        for (int s = 0; s < 4; ++s)
            qf[s] = *(const short8*)(Qp + s * 16 + hi * 8);

        floatx16 o0, o1, lacc;
#pragma unroll
        for (int i = 0; i < 16; ++i) { o0[i] = 0.f; o1[i] = 0.f; lacc[i] = 0.f; }

        short8 kreg[2], vreg[2];
#pragma unroll
        for (int it = 0; it < 2; ++it) {
            int idx = it * 256 + tid;
            kreg[it] = *(const short8*)(Kp + idx * 8);
            vreg[it] = *(const short8*)(Vp + (idx >> 3) * 2048 + (idx & 7) * 8);
        }

        int qg = q0 + qh * 32 + l31;
        int krow = (kh * 32 + l31) * 68 + hi * 8;
        for (int kt = 0; kt <= qb; ++kt) {
            int kt0 = kt << 6;
            __syncthreads();   // also orders prev pass's Lo reads before these KV writes
#pragma unroll
            for (int it = 0; it < 2; ++it) {
                int idx = it * 256 + tid;
                *(short8*)&Ks[(idx >> 3) * 68 + (idx & 7) * 8] = kreg[it];
                *(short8*)&Vs[(idx >> 3) * 68 + (idx & 7) * 8] = vreg[it];
            }
            __syncthreads();
            if (kt < qb) {
                int s0 = (kt + 1) << 6;
#pragma unroll
                for (int it = 0; it < 2; ++it) {
                    int idx = it * 256 + tid;
                    kreg[it] = *(const short8*)(Kp + s0 * 64 + idx * 8);
                    vreg[it] = *(const short8*)(Vp + (idx >> 3) * 2048 + s0 + (idx & 7) * 8);
                }
            }
            bool diag = (kt == qb);

            // QK^T: z[kp32][q32], A = K rows (this wave's kp-half), B = Q
            floatx16 z;
#pragma unroll
            for (int i = 0; i < 16; ++i) z[i] = 0.f;
#pragma unroll
            for (int s = 0; s < 4; ++s) {
                short8 kf = *(const short8*)&Ks[krow + s * 16];
                z = __builtin_amdgcn_mfma_f32_32x32x16_bf16(kf, qf[s], z, 0, 0, 0);
            }

            // mask + exp in place
            int kpb_ = kt0 + kh * 32 + 4 * hi;
#pragma unroll
            for (int r = 0; r < 16; ++r) {
                float s = z[r];
                if (diag) s = (kpb_ + (r & 3) + 8 * (r >> 2) > qg) ? -1e30f : s;
                z[r] = exp2f(s);
            }
            // pack to bf16 words: w[t][u2] = P pair at kp = 2*u2 + 8*t + 4*hi
            unsigned w[4][2];
#pragma unroll
            for (int t2 = 0; t2 < 4; ++t2)
#pragma unroll
                for (int u2 = 0; u2 < 2; ++u2) {
                    union { unsigned u; __hip_bfloat162 h2; } pk;
                    pk.h2 = __float22bfloat162_rn(
                        make_float2(z[t2 * 4 + u2 * 2], z[t2 * 4 + u2 * 2 + 1]));
                    w[t2][u2] = pk.u;
                }
            // PV + row-sum: per k-step s (kp base s*16), assemble A-frag via half exchange
#pragma unroll
            for (int s = 0; s < 2; ++s) {
                unsigned s0w = hi ? w[2 * s][0] : w[2 * s + 1][0];
                unsigned s1w = hi ? w[2 * s][1] : w[2 * s + 1][1];
                unsigned r0 = (unsigned)__shfl_xor((int)s0w, 32);
                unsigned r1 = (unsigned)__shfl_xor((int)s1w, 32);
                union { unsigned u[4]; short8 v; } pa;
                if (hi == 0) { pa.u[0] = w[2*s][0]; pa.u[1] = w[2*s][1]; pa.u[2] = r0; pa.u[3] = r1; }
                else         { pa.u[0] = r0; pa.u[1] = r1; pa.u[2] = w[2*s+1][0]; pa.u[3] = w[2*s+1][1]; }
                short8 vb0 = *(const short8*)&Vs[l31 * 68 + kh * 32 + s * 16 + hi * 8];
                short8 vb1 = *(const short8*)&Vs[(32 + l31) * 68 + kh * 32 + s * 16 + hi * 8];
                o0   = __builtin_amdgcn_mfma_f32_32x32x16_bf16(pa.v, vb0,   o0,   0, 0, 0);
                o1   = __builtin_amdgcn_mfma_f32_32x32x16_bf16(pa.v, vb1,   o1,   0, 0, 0);
                lacc = __builtin_amdgcn_mfma_f32_32x32x16_bf16(pa.v, vones, lacc, 0, 0, 0);
            }
        }

        // ---- epilogue: overlay Lo/Ll on KV (K/V reads of this pass done after barrier) ----
        __syncthreads();
        float* Lo = (float*)KV;           // [2][32][64] = 16 KB
        float* Ll = (float*)KV + 4096;    // [2][32] = 256 B
        if (kh == 1) {
#pragma unroll
            for (int r = 0; r < 16; ++r) {
                int q = (r & 3) + 8 * (r >> 2) + 4 * hi;
                Lo[(qh * 32 + q) * 64 + l31]      = o0[r];
                Lo[(qh * 32 + q) * 64 + 32 + l31] = o1[r];
            }
            if (l31 == 0) {
#pragma unroll
                for (int r = 0; r < 16; ++r)
                    Ll[qh * 32 + (r & 3) + 8 * (r >> 2) + 4 * hi] = lacc[r];
            }
        }
        __syncthreads();
        if (kh == 0) {
#pragma unroll
            for (int r = 0; r < 16; ++r) {
                int q = (r & 3) + 8 * (r >> 2) + 4 * hi;
                float linv = 1.0f / (lacc[r] + Ll[qh * 32 + q]);
                int qgl = q0 + qh * 32 + q;
                size_t base = (size_t)(b * 2048 + qgl) * 1024 + h * 64;
                aout[base + l31]      = f2bf((o0[r] + Lo[(qh * 32 + q) * 64 + l31]) * linv);
                aout[base + 32 + l31] = f2bf((o1[r] + Lo[(qh * 32 + q) * 64 + 32 + l31]) * linv);
            }
        }
    }
}

// ---------------- proj GEMM: 256x128 tile, BK=64, counted-vmcnt, 16 waves, zero tail ------
// (unchanged)
__global__ __launch_bounds__(1024) void gemm_proj_kernel(const ushort_t* __restrict__ A,
                                                         const ushort_t* __restrict__ Bt,
                                                         const float* __restrict__ bias,
                                                         float* __restrict__ Cout) {
    extern __shared__ __align__(16) ushort_t lds[];

    int bid = blockIdx.x;
    int wg = (bid & 7) * 32 + (bid >> 3);      // XCD-bijective swizzle (256 % 8 == 0)
    int bm = wg & 31, bn = wg >> 5;
    int m0 = bm << 8, n0 = bn << 7;

    int tid = threadIdx.x;
    int wave = tid >> 6, lane = tid & 63;
    int c = lane & 15, g = lane >> 4;
    int wm = wave >> 2, wn = wave & 3;

    int row0 = tid >> 3;
    int sch  = (tid & 7) ^ (row0 & 7);
    size_t aoff = (size_t)(m0 + row0) * 1024 + sch * 8;
    size_t boff = (size_t)(n0 + row0) * 1024 + sch * 8;

    int co0 = (g * 8) ^ ((c & 7) << 3);
    int co1 = co0 ^ 32;

    floatx4 acc[4][2];
    short8 a[4][2], bb[2];
#pragma unroll
    for (int i2 = 0; i2 < 4; ++i2)
#pragma unroll
        for (int j2 = 0; j2 < 2; ++j2) { floatx4 z = {0.f,0.f,0.f,0.f}; acc[i2][j2] = z; }

    auto stA = [&](int t, int buf) {
        const ushort_t* s = A + aoff + (size_t)t * 64;
        ushort_t* d = lds + buf * 16384 + tid * 8;
        async_ld16(s, d);
        async_ld16(s + 131072, d + 8192);
    };
    auto stB = [&](int t, int buf) {
        async_ld16(Bt + boff + (size_t)t * 64, lds + 32768 + buf * 8192 + tid * 8);
    };
    auto ld_a = [&](int buf) {
#pragma unroll
        for (int mi = 0; mi < 4; ++mi) {
            int ro = buf * 16384 + (wm * 64 + mi * 16 + c) * 64;
            a[mi][0] = *(const short8*)&lds[ro + co0];
            a[mi][1] = *(const short8*)&lds[ro + co1];
        }
    };
    auto ld_b = [&](int buf, int nii) {
        int ro = 32768 + buf * 8192 + (wn * 32 + nii * 16 + c) * 64;
        bb[0] = *(const short8*)&lds[ro + co0];
        bb[1] = *(const short8*)&lds[ro + co1];
    };
    auto mm = [&](int nii) {
        asm volatile("s_barrier" ::: "memory");
        asm volatile("s_waitcnt lgkmcnt(0)" ::: "memory");
        __builtin_amdgcn_s_setprio(1);
#pragma unroll
        for (int mi = 0; mi < 4; ++mi)
#pragma unroll
            for (int ks = 0; ks < 2; ++ks)
                acc[mi][nii] = __builtin_amdgcn_mfma_f32_16x16x32_bf16(
                    a[mi][ks], bb[ks], acc[mi][nii], 0, 0, 0);
        __builtin_amdgcn_s_setprio(0);
        asm volatile("s_barrier" ::: "memory");
    };

    stA(0, 0); stB(0, 0);
    stA(1, 1); stB(1, 1);
    asm volatile("s_waitcnt vmcnt(3)" ::: "memory");
    asm volatile("s_barrier" ::: "memory");

#pragma unroll 1
    for (int t = 0; t < 14; ++t) {
        int buf = t & 1;
        ld_a(buf); ld_b(buf, 0);
        mm(0);
        ld_b(buf, 1);
        stA(t + 2, buf); stB(t + 2, buf);
        asm volatile("s_waitcnt vmcnt(3)" ::: "memory");
        mm(1);
    }
    ld_a(0); ld_b(0, 0);
    mm(0);
    ld_b(0, 1);
    asm volatile("s_waitcnt vmcnt(0)" ::: "memory");
    mm(1);
    ld_a(1); ld_b(1, 0);
    mm(0);
    ld_b(1, 1);
    mm(1);

    float bv[2];
#pragma unroll
    for (int nii = 0; nii < 2; ++nii) bv[nii] = bias[n0 + wn * 32 + nii * 16 + c];
#pragma unroll
    for (int mi = 0; mi < 4; ++mi)
#pragma unroll
        for (int nii = 0; nii < 2; ++nii)
#pragma unroll
            for (int r = 0; r < 4; ++r) {
                int row = m0 + wm * 64 + mi * 16 + g * 4 + r;
                int col = n0 + wn * 32 + nii * 16 + c;
                Cout[(size_t)row * 1024 + col] = acc[mi][nii][r] + bv[nii];
            }
}

extern "C" void kernel_launch(void* const* d_in, const int* in_sizes, int n_in,
                              void* d_out, int out_size, void* d_ws, size_t ws_size,
                              hipStream_t stream) {
    const float* x        = (const float*)d_in[0];
    const float* c_attn_w = (const float*)d_in[1];
    const float* c_attn_b = (const float*)d_in[2];
    const float* c_proj_w = (const float*)d_in[3];
    const float* c_proj_b = (const float*)d_in[4];
    float* out = (float*)d_out;

    char* ws = (char*)d_ws;
    ushort_t* xb     = (ushort_t*)(ws);              // 16 MB; reused as attn output 'a'
    ushort_t* wqkvT  = (ushort_t*)(ws + 16777216);   // 6 MB
    ushort_t* wprojT = (ushort_t*)(ws + 23068672);   // 2 MB
    ushort_t* qbuf   = (ushort_t*)(ws + 25165824);   // 16 MB  [bh][s][64]  (pre-scaled)
    ushort_t* kbuf   = (ushort_t*)(ws + 41943040);   // 16 MB  [bh][s][64]
    ushort_t* vtbuf  = (ushort_t*)(ws + 58720256);   // 16 MB  [bh][64][2048]

    static bool s_attr_set = false;
    if (!s_attr_set) {
        (void)hipFuncSetAttribute(reinterpret_cast<const void*>(gemm_qkv_kernel),
                                  hipFuncAttributeMaxDynamicSharedMemorySize, 131072);
        (void)hipFuncSetAttribute(reinterpret_cast<const void*>(gemm_proj_kernel),
                                  hipFuncAttributeMaxDynamicSharedMemorySize, 98304);
        s_attr_set = true;
    }

    prep_kernel<<<12288, 256, 0, stream>>>(x, c_attn_w, c_proj_w, xb, wqkvT, wprojT);
    gemm_qkv_kernel<<<512, 1024, 131072, stream>>>(xb, wqkvT, c_attn_b, qbuf, kbuf, vtbuf);
    attn_kernel<<<1024, 256, 0, stream>>>(qbuf, kbuf, vtbuf, xb);
    gemm_proj_kernel<<<256, 1024, 98304, stream>>>(xb, wprojT, c_proj_b, out);
}

// Round 12
// 255.590 us; speedup vs baseline: 1.4381x; 1.4381x over previous
//
#include <hip/hip_runtime.h>
#include <hip/hip_bf16.h>

typedef unsigned short ushort_t;
typedef __attribute__((ext_vector_type(8))) short short8;
typedef __attribute__((ext_vector_type(4))) float floatx4;
typedef __attribute__((ext_vector_type(16))) float floatx16;

#define LOG2E 1.4426950408889634f

__device__ __forceinline__ unsigned short f2bf(float f) {
    unsigned u = __float_as_uint(f);
    u += 0x7FFF + ((u >> 16) & 1);   // RNE
    return (unsigned short)(u >> 16);
}

__device__ __forceinline__ void async_ld16(const void* gptr, void* lptr) {
    typedef const __attribute__((address_space(1))) unsigned int TG;
    typedef __attribute__((address_space(3))) unsigned int TL;
    __builtin_amdgcn_global_load_lds((TG*)(unsigned long long)gptr,
                                     (TL*)(unsigned)(unsigned long long)lptr,
                                     16, 0, 0);
}

// ---------------- fused prep: x->bf16 | w_qkv transpose | w_proj transpose ----------------
__global__ __launch_bounds__(256) void prep_kernel(const float* __restrict__ x,
                                                   const float* __restrict__ wqkv,
                                                   const float* __restrict__ wproj,
                                                   ushort_t* __restrict__ xb,
                                                   ushort_t* __restrict__ wqkvT,
                                                   ushort_t* __restrict__ wprojT) {
    __shared__ float t[32][33];
    int bx = blockIdx.x;
    if (bx < 8192) {
        int i = bx * 256 + threadIdx.x;
        float4 v = ((const float4*)x)[i];
        unsigned long long r = (unsigned long long)f2bf(v.x)
                             | ((unsigned long long)f2bf(v.y) << 16)
                             | ((unsigned long long)f2bf(v.z) << 32)
                             | ((unsigned long long)f2bf(v.w) << 48);
        ((unsigned long long*)xb)[i] = r;
        return;
    }
    const float* in; ushort_t* out; int R, C, bidx;
    if (bx < 8192 + 3072) { in = wqkv; out = wqkvT; R = 1024; C = 3072; bidx = bx - 8192; }
    else                  { in = wproj; out = wprojT; R = 1024; C = 1024; bidx = bx - 11264; }
    int nbc = C >> 5;
    int bc = bidx % nbc, br = bidx / nbc;
    int tx = threadIdx.x & 31, ty = threadIdx.x >> 5;   // 32 x 8
    int r0 = br << 5, c0 = bc << 5;
#pragma unroll
    for (int j = 0; j < 4; ++j)
        t[ty + j * 8][tx] = in[(size_t)(r0 + ty + j * 8) * C + c0 + tx];
    __syncthreads();
#pragma unroll
    for (int j = 0; j < 4; ++j)
        out[(size_t)(c0 + ty + j * 8) * R + r0 + tx] = f2bf(t[tx][ty + j * 8]);
}

// ---------------- QKV GEMM: 128x384 tile, BK=64, counted-vmcnt, 16 waves, zero tail -------
__global__ __launch_bounds__(1024) void gemm_qkv_kernel(const ushort_t* __restrict__ A,
                                                        const ushort_t* __restrict__ Bt,
                                                        const float* __restrict__ bias,
                                                        ushort_t* __restrict__ qbuf,
                                                        ushort_t* __restrict__ kbuf,
                                                        ushort_t* __restrict__ vtbuf) {
    extern __shared__ __align__(16) ushort_t lds[];

    int bid = blockIdx.x;
    int wg = (bid & 7) * 64 + (bid >> 3);      // XCD-bijective swizzle (512 % 8 == 0)
    int bm = wg & 63, bn = wg >> 6;            // 64 x 8
    int m0 = bm << 7, n0 = bn * 384;

    int tid = threadIdx.x;
    int wave = tid >> 6, lane = tid & 63;
    int c = lane & 15, g = lane >> 4;
    int wm = wave >> 3, wn = wave & 7;

    int row0 = tid >> 3;
    int sch  = (tid & 7) ^ (row0 & 7);
    size_t aoff = (size_t)(m0 + row0) * 1024 + sch * 8;
    size_t boff = (size_t)(n0 + row0) * 1024 + sch * 8;

    int co0 = (g * 8) ^ ((c & 7) << 3);
    int co1 = co0 ^ 32;

    floatx4 acc[4][3];
    short8 a[4][2], bb[2];
#pragma unroll
    for (int i2 = 0; i2 < 4; ++i2)
#pragma unroll
        for (int j2 = 0; j2 < 3; ++j2) { floatx4 z = {0.f,0.f,0.f,0.f}; acc[i2][j2] = z; }

    auto stA = [&](int t, int buf) {
        async_ld16(A + aoff + (size_t)t * 64, lds + buf * 8192 + tid * 8);
    };
    auto stB = [&](int t, int buf) {
        const ushort_t* s = Bt + boff + (size_t)t * 64;
        ushort_t* d = lds + 16384 + buf * 24576 + tid * 8;
        async_ld16(s, d);
        async_ld16(s + 131072, d + 8192);
        async_ld16(s + 262144, d + 16384);
    };
    auto ld_a = [&](int buf) {
#pragma unroll
        for (int mi = 0; mi < 4; ++mi) {
            int ro = buf * 8192 + (wm * 64 + mi * 16 + c) * 64;
            a[mi][0] = *(const short8*)&lds[ro + co0];
            a[mi][1] = *(const short8*)&lds[ro + co1];
        }
    };
    auto ld_b = [&](int buf, int nii) {
        int ro = 16384 + buf * 24576 + (wn * 48 + nii * 16 + c) * 64;
        bb[0] = *(const short8*)&lds[ro + co0];
        bb[1] = *(const short8*)&lds[ro + co1];
    };
    auto mm = [&](int nii) {
        asm volatile("s_barrier" ::: "memory");
        asm volatile("s_waitcnt lgkmcnt(0)" ::: "memory");
        __builtin_amdgcn_s_setprio(1);
#pragma unroll
        for (int mi = 0; mi < 4; ++mi)
#pragma unroll
            for (int ks = 0; ks < 2; ++ks)
                acc[mi][nii] = __builtin_amdgcn_mfma_f32_16x16x32_bf16(
                    a[mi][ks], bb[ks], acc[mi][nii], 0, 0, 0);
        __builtin_amdgcn_s_setprio(0);
        asm volatile("s_barrier" ::: "memory");
    };

    stA(0, 0); stB(0, 0);
    stA(1, 1); stB(1, 1);
    asm volatile("s_waitcnt vmcnt(4)" ::: "memory");
    asm volatile("s_barrier" ::: "memory");

#pragma unroll 1
    for (int t = 0; t < 14; ++t) {
        int buf = t & 1;
        ld_a(buf); ld_b(buf, 0);
        mm(0);
        ld_b(buf, 1);
        mm(1);
        ld_b(buf, 2);
        stA(t + 2, buf); stB(t + 2, buf);
        asm volatile("s_waitcnt vmcnt(4)" ::: "memory");
        mm(2);
    }
    ld_a(0); ld_b(0, 0);
    mm(0);
    ld_b(0, 1);
    mm(1);
    ld_b(0, 2);
    asm volatile("s_waitcnt vmcnt(0)" ::: "memory");
    mm(2);
    ld_a(1); ld_b(1, 0);
    mm(0);
    ld_b(1, 1);
    mm(1);
    ld_b(1, 2);
    mm(2);

    int b = m0 >> 11, sbase = m0 & 2047;
    float bv[3], scl[3];
    int headf[3], cinh[3], secf[3];
#pragma unroll
    for (int nii = 0; nii < 3; ++nii) {
        int cb = wn * 48 + nii * 16;
        bv[nii]   = bias[n0 + cb + c];
        headf[nii] = cb >> 6;
        cinh[nii]  = (cb & 63) + c;
        secf[nii]  = (n0 + cb) >> 10;
        scl[nii]   = (secf[nii] == 0) ? (0.125f * LOG2E) : 1.0f;
    }

    __syncthreads();

#pragma unroll
    for (int nii = 0; nii < 3; ++nii) {
        if (secf[nii] < 2) {
#pragma unroll
            for (int mi = 0; mi < 4; ++mi)
#pragma unroll
                for (int r = 0; r < 4; ++r) {
                    int row = wm * 64 + mi * 16 + g * 4 + r;
                    lds[headf[nii] * 9216 + row * 72 + cinh[nii]] =
                        f2bf((acc[mi][nii][r] + bv[nii]) * scl[nii]);
                }
        } else {
#pragma unroll
            for (int mi = 0; mi < 4; ++mi) {
                int d = cinh[nii];
                int s0 = wm * 64 + mi * 16 + g * 4;
                unsigned long long pk =
                      (unsigned long long)f2bf(acc[mi][nii][0] + bv[nii])
                    | ((unsigned long long)f2bf(acc[mi][nii][1] + bv[nii]) << 16)
                    | ((unsigned long long)f2bf(acc[mi][nii][2] + bv[nii]) << 32)
                    | ((unsigned long long)f2bf(acc[mi][nii][3] + bv[nii]) << 48);
                *(unsigned long long*)&lds[headf[nii] * 9216 + d * 136 + s0] = pk;
            }
        }
    }
    __syncthreads();

#pragma unroll 1
    for (int hl = 0; hl < 6; ++hl) {
        int colg = n0 + hl * 64;
        int sech = colg >> 10;
        int hg = (colg & 1023) >> 6;
        size_t bh = (size_t)(b * 16 + hg);
        if (sech < 2) {
            int row = tid >> 3, ch = tid & 7;
            ushort_t* dst = (sech == 0 ? qbuf : kbuf) + bh * 131072
                          + (size_t)(sbase + row) * 64 + ch * 8;
            *(short8*)dst = *(const short8*)&lds[hl * 9216 + row * 72 + ch * 8];
        } else {
            int d = tid >> 4, sq = tid & 15;
            ushort_t* dst = vtbuf + bh * 131072 + (size_t)d * 2048 + sbase + sq * 8;
            *(short8*)dst = *(const short8*)&lds[hl * 9216 + d * 136 + sq * 8];
        }
    }
}

// ---------------- flash attention: 32x32 MFMA, in-register softmax, kp-split waves --------
// EXACT R6-measured configuration (74.1 µs): separate Lo/Ll LDS (34.3 KB total), (256,4),
// lacc ones-MFMA row-sum, exp2f, LPT 2048 blocks. R7-R11 showed every perturbation of this
// kernel's occupancy/LDS/register envelope (overlay->17.4KB residency-up, (256,5) VGPR cap,
// paired q-tiles) loses 100+ µs via spill or residency-induced slowdown. Local optimum —
// restored verbatim and frozen.
__global__ __launch_bounds__(256, 4) void attn_kernel(const ushort_t* __restrict__ qb_,
                                                      const ushort_t* __restrict__ kb_,
                                                      const ushort_t* __restrict__ vtb_,
                                                      ushort_t* __restrict__ aout) {
    __shared__ __align__(16) ushort_t Ks[64 * 68];       // [kp][d] stride 68
    __shared__ __align__(16) ushort_t Vs[64 * 68];       // [d][kp] stride 68
    __shared__ __align__(16) float Lo[2][32][64];        // kh=1 partial O
    __shared__ float Ll[2][32];                          // kh=1 partial row-sum
    int bx = blockIdx.x;
    int qb = 31 - (bx >> 6);          // LPT: longest blocks dispatch first
    int bhix = bx & 63;
    int b = bhix >> 4, h = bhix & 15;
    int q0 = qb << 6;
    int tid = threadIdx.x, wave = tid >> 6, lane = tid & 63;
    int qh = wave >> 1, kh = wave & 1;
    int l31 = lane & 31, hi = lane >> 5;
    size_t bh = (size_t)(b * 16 + h);

    const ushort_t* Qp = qb_ + (bh * 2048 + q0 + qh * 32 + l31) * 64;
    const ushort_t* Kp = kb_ + bh * 131072;
    const ushort_t* Vp = vtb_ + bh * 131072;

    // Q as B-operand: col=l31 (q row), k elements d = s*16 + hi*8 + j
    short8 qf[4];
#pragma unroll
    for (int s = 0; s < 4; ++s)
        qf[s] = *(const short8*)(Qp + s * 16 + hi * 8);

    short8 vones;
#pragma unroll
    for (int j = 0; j < 8; ++j) vones[j] = (short)0x3F80;   // bf16 1.0

    floatx16 o0, o1, lacc;
#pragma unroll
    for (int i = 0; i < 16; ++i) { o0[i] = 0.f; o1[i] = 0.f; lacc[i] = 0.f; }

    short8 kreg[2], vreg[2];
#pragma unroll
    for (int it = 0; it < 2; ++it) {
        int idx = it * 256 + tid;
        kreg[it] = *(const short8*)(Kp + idx * 8);
        vreg[it] = *(const short8*)(Vp + (idx >> 3) * 2048 + (idx & 7) * 8);
    }

    int qg = q0 + qh * 32 + l31;
    int krow = (kh * 32 + l31) * 68 + hi * 8;
    for (int kt = 0; kt <= qb; ++kt) {
        int kt0 = kt << 6;
        __syncthreads();
#pragma unroll
        for (int it = 0; it < 2; ++it) {
            int idx = it * 256 + tid;
            *(short8*)&Ks[(idx >> 3) * 68 + (idx & 7) * 8] = kreg[it];
            *(short8*)&Vs[(idx >> 3) * 68 + (idx & 7) * 8] = vreg[it];
        }
        __syncthreads();
        if (kt < qb) {
            int s0 = (kt + 1) << 6;
#pragma unroll
            for (int it = 0; it < 2; ++it) {
                int idx = it * 256 + tid;
                kreg[it] = *(const short8*)(Kp + s0 * 64 + idx * 8);
                vreg[it] = *(const short8*)(Vp + (idx >> 3) * 2048 + s0 + (idx & 7) * 8);
            }
        }
        bool diag = (kt == qb);

        // QK^T: z[kp32][q32], A = K rows (this wave's kp-half), B = Q
        floatx16 z;
#pragma unroll
        for (int i = 0; i < 16; ++i) z[i] = 0.f;
#pragma unroll
        for (int s = 0; s < 4; ++s) {
            short8 kf = *(const short8*)&Ks[krow + s * 16];
            z = __builtin_amdgcn_mfma_f32_32x32x16_bf16(kf, qf[s], z, 0, 0, 0);
        }

        // mask + exp in place: z[r] -> P, kp = kt0 + kh*32 + (r&3)+8*(r>>2)+4*hi, q col = qg
        int kpb_ = kt0 + kh * 32 + 4 * hi;
#pragma unroll
        for (int r = 0; r < 16; ++r) {
            float s = z[r];
            if (diag) s = (kpb_ + (r & 3) + 8 * (r >> 2) > qg) ? -1e30f : s;
            z[r] = exp2f(s);
        }
        // pack to bf16 words: w[t][u2] = P pair at kp = 2*u2 + 8*t + 4*hi
        unsigned w[4][2];
#pragma unroll
        for (int t2 = 0; t2 < 4; ++t2)
#pragma unroll
            for (int u2 = 0; u2 < 2; ++u2) {
                union { unsigned u; __hip_bfloat162 h2; } pk;
                pk.h2 = __float22bfloat162_rn(
                    make_float2(z[t2 * 4 + u2 * 2], z[t2 * 4 + u2 * 2 + 1]));
                w[t2][u2] = pk.u;
            }
        // PV + row-sum: per k-step s (kp base s*16), assemble A-frag via half exchange
#pragma unroll
        for (int s = 0; s < 2; ++s) {
            unsigned s0w = hi ? w[2 * s][0] : w[2 * s + 1][0];
            unsigned s1w = hi ? w[2 * s][1] : w[2 * s + 1][1];
            unsigned r0 = (unsigned)__shfl_xor((int)s0w, 32);
            unsigned r1 = (unsigned)__shfl_xor((int)s1w, 32);
            union { unsigned u[4]; short8 v; } pa;
            if (hi == 0) { pa.u[0] = w[2*s][0]; pa.u[1] = w[2*s][1]; pa.u[2] = r0; pa.u[3] = r1; }
            else         { pa.u[0] = r0; pa.u[1] = r1; pa.u[2] = w[2*s+1][0]; pa.u[3] = w[2*s+1][1]; }
            short8 vb0 = *(const short8*)&Vs[l31 * 68 + kh * 32 + s * 16 + hi * 8];
            short8 vb1 = *(const short8*)&Vs[(32 + l31) * 68 + kh * 32 + s * 16 + hi * 8];
            o0   = __builtin_amdgcn_mfma_f32_32x32x16_bf16(pa.v, vb0,   o0,   0, 0, 0);
            o1   = __builtin_amdgcn_mfma_f32_32x32x16_bf16(pa.v, vb1,   o1,   0, 0, 0);
            lacc = __builtin_amdgcn_mfma_f32_32x32x16_bf16(pa.v, vones, lacc, 0, 0, 0);
        }
    }

    // cross-kp-half reduction: kh=1 writes partials, kh=0 adds, normalizes, stores.
    if (kh == 1) {
#pragma unroll
        for (int r = 0; r < 16; ++r) {
            int q = (r & 3) + 8 * (r >> 2) + 4 * hi;
            Lo[qh][q][l31]      = o0[r];
            Lo[qh][q][32 + l31] = o1[r];
        }
        if (l31 == 0) {
#pragma unroll
            for (int r = 0; r < 16; ++r)
                Ll[qh][(r & 3) + 8 * (r >> 2) + 4 * hi] = lacc[r];
        }
    }
    __syncthreads();
    if (kh == 0) {
#pragma unroll
        for (int r = 0; r < 16; ++r) {
            int q = (r & 3) + 8 * (r >> 2) + 4 * hi;
            float linv = 1.0f / (lacc[r] + Ll[qh][q]);
            int qgl = q0 + qh * 32 + q;
            size_t base = (size_t)(b * 2048 + qgl) * 1024 + h * 64;
            aout[base + l31]      = f2bf((o0[r] + Lo[qh][q][l31]) * linv);
            aout[base + 32 + l31] = f2bf((o1[r] + Lo[qh][q][32 + l31]) * linv);
        }
    }
}

// ---------------- proj GEMM: 256x128 tile, BK=64, counted-vmcnt, 16 waves, zero tail ------
__global__ __launch_bounds__(1024) void gemm_proj_kernel(const ushort_t* __restrict__ A,
                                                         const ushort_t* __restrict__ Bt,
                                                         const float* __restrict__ bias,
                                                         float* __restrict__ Cout) {
    extern __shared__ __align__(16) ushort_t lds[];

    int bid = blockIdx.x;
    int wg = (bid & 7) * 32 + (bid >> 3);      // XCD-bijective swizzle (256 % 8 == 0)
    int bm = wg & 31, bn = wg >> 5;
    int m0 = bm << 8, n0 = bn << 7;

    int tid = threadIdx.x;
    int wave = tid >> 6, lane = tid & 63;
    int c = lane & 15, g = lane >> 4;
    int wm = wave >> 2, wn = wave & 3;

    int row0 = tid >> 3;
    int sch  = (tid & 7) ^ (row0 & 7);
    size_t aoff = (size_t)(m0 + row0) * 1024 + sch * 8;
    size_t boff = (size_t)(n0 + row0) * 1024 + sch * 8;

    int co0 = (g * 8) ^ ((c & 7) << 3);
    int co1 = co0 ^ 32;

    floatx4 acc[4][2];
    short8 a[4][2], bb[2];
#pragma unroll
    for (int i2 = 0; i2 < 4; ++i2)
#pragma unroll
        for (int j2 = 0; j2 < 2; ++j2) { floatx4 z = {0.f,0.f,0.f,0.f}; acc[i2][j2] = z; }

    auto stA = [&](int t, int buf) {
        const ushort_t* s = A + aoff + (size_t)t * 64;
        ushort_t* d = lds + buf * 16384 + tid * 8;
        async_ld16(s, d);
        async_ld16(s + 131072, d + 8192);
    };
    auto stB = [&](int t, int buf) {
        async_ld16(Bt + boff + (size_t)t * 64, lds + 32768 + buf * 8192 + tid * 8);
    };
    auto ld_a = [&](int buf) {
#pragma unroll
        for (int mi = 0; mi < 4; ++mi) {
            int ro = buf * 16384 + (wm * 64 + mi * 16 + c) * 64;
            a[mi][0] = *(const short8*)&lds[ro + co0];
            a[mi][1] = *(const short8*)&lds[ro + co1];
        }
    };
    auto ld_b = [&](int buf, int nii) {
        int ro = 32768 + buf * 8192 + (wn * 32 + nii * 16 + c) * 64;
        bb[0] = *(const short8*)&lds[ro + co0];
        bb[1] = *(const short8*)&lds[ro + co1];
    };
    auto mm = [&](int nii) {
        asm volatile("s_barrier" ::: "memory");
        asm volatile("s_waitcnt lgkmcnt(0)" ::: "memory");
        __builtin_amdgcn_s_setprio(1);
#pragma unroll
        for (int mi = 0; mi < 4; ++mi)
#pragma unroll
            for (int ks = 0; ks < 2; ++ks)
                acc[mi][nii] = __builtin_amdgcn_mfma_f32_16x16x32_bf16(
                    a[mi][ks], bb[ks], acc[mi][nii], 0, 0, 0);
        __builtin_amdgcn_s_setprio(0);
        asm volatile("s_barrier" ::: "memory");
    };

    stA(0, 0); stB(0, 0);
    stA(1, 1); stB(1, 1);
    asm volatile("s_waitcnt vmcnt(3)" ::: "memory");
    asm volatile("s_barrier" ::: "memory");

#pragma unroll 1
    for (int t = 0; t < 14; ++t) {
        int buf = t & 1;
        ld_a(buf); ld_b(buf, 0);
        mm(0);
        ld_b(buf, 1);
        stA(t + 2, buf); stB(t + 2, buf);
        asm volatile("s_waitcnt vmcnt(3)" ::: "memory");
        mm(1);
    }
    ld_a(0); ld_b(0, 0);
    mm(0);
    ld_b(0, 1);
    asm volatile("s_waitcnt vmcnt(0)" ::: "memory");
    mm(1);
    ld_a(1); ld_b(1, 0);
    mm(0);
    ld_b(1, 1);
    mm(1);

    float bv[2];
#pragma unroll
    for (int nii = 0; nii < 2; ++nii) bv[nii] = bias[n0 + wn * 32 + nii * 16 + c];
#pragma unroll
    for (int mi = 0; mi < 4; ++mi)
#pragma unroll
        for (int nii = 0; nii < 2; ++nii)
#pragma unroll
            for (int r = 0; r < 4; ++r) {
                int row = m0 + wm * 64 + mi * 16 + g * 4 + r;
                int col = n0 + wn * 32 + nii * 16 + c;
                Cout[(size_t)row * 1024 + col] = acc[mi][nii][r] + bv[nii];
            }
}

extern "C" void kernel_launch(void* const* d_in, const int* in_sizes, int n_in,
                              void* d_out, int out_size, void* d_ws, size_t ws_size,
                              hipStream_t stream) {
    const float* x        = (const float*)d_in[0];
    const float* c_attn_w = (const float*)d_in[1];
    const float* c_attn_b = (const float*)d_in[2];
    const float* c_proj_w = (const float*)d_in[3];
    const float* c_proj_b = (const float*)d_in[4];
    float* out = (float*)d_out;

    char* ws = (char*)d_ws;
    ushort_t* xb     = (ushort_t*)(ws);              // 16 MB; reused as attn output 'a'
    ushort_t* wqkvT  = (ushort_t*)(ws + 16777216);   // 6 MB
    ushort_t* wprojT = (ushort_t*)(ws + 23068672);   // 2 MB
    ushort_t* qbuf   = (ushort_t*)(ws + 25165824);   // 16 MB  [bh][s][64]  (pre-scaled)
    ushort_t* kbuf   = (ushort_t*)(ws + 41943040);   // 16 MB  [bh][s][64]
    ushort_t* vtbuf  = (ushort_t*)(ws + 58720256);   // 16 MB  [bh][64][2048]

    static bool s_attr_set = false;
    if (!s_attr_set) {
        (void)hipFuncSetAttribute(reinterpret_cast<const void*>(gemm_qkv_kernel),
                                  hipFuncAttributeMaxDynamicSharedMemorySize, 131072);
        (void)hipFuncSetAttribute(reinterpret_cast<const void*>(gemm_proj_kernel),
                                  hipFuncAttributeMaxDynamicSharedMemorySize, 98304);
        s_attr_set = true;
    }

    prep_kernel<<<12288, 256, 0, stream>>>(x, c_attn_w, c_proj_w, xb, wqkvT, wprojT);
    gemm_qkv_kernel<<<512, 1024, 131072, stream>>>(xb, wqkvT, c_attn_b, qbuf, kbuf, vtbuf);
    attn_kernel<<<2048, 256, 0, stream>>>(qbuf, kbuf, vtbuf, xb);
    gemm_proj_kernel<<<256, 1024, 98304, stream>>>(xb, wprojT, c_proj_b, out);
}

// Round 13
// 250.052 us; speedup vs baseline: 1.4699x; 1.0221x over previous
//
#include <hip/hip_runtime.h>
#include <hip/hip_bf16.h>

typedef unsigned short ushort_t;
typedef __attribute__((ext_vector_type(8))) short short8;
typedef __attribute__((ext_vector_type(4))) float floatx4;
typedef __attribute__((ext_vector_type(16))) float floatx16;

#define LOG2E 1.4426950408889634f

__device__ __forceinline__ unsigned short f2bf(float f) {
    unsigned u = __float_as_uint(f);
    u += 0x7FFF + ((u >> 16) & 1);   // RNE
    return (unsigned short)(u >> 16);
}

__device__ __forceinline__ void async_ld16(const void* gptr, void* lptr) {
    typedef const __attribute__((address_space(1))) unsigned int TG;
    typedef __attribute__((address_space(3))) unsigned int TL;
    __builtin_amdgcn_global_load_lds((TG*)(unsigned long long)gptr,
                                     (TL*)(unsigned)(unsigned long long)lptr,
                                     16, 0, 0);
}

// ---------------- fused prep: x->bf16 | w_qkv transpose | w_proj transpose ----------------
__global__ __launch_bounds__(256) void prep_kernel(const float* __restrict__ x,
                                                   const float* __restrict__ wqkv,
                                                   const float* __restrict__ wproj,
                                                   ushort_t* __restrict__ xb,
                                                   ushort_t* __restrict__ wqkvT,
                                                   ushort_t* __restrict__ wprojT) {
    __shared__ float t[32][33];
    int bx = blockIdx.x;
    if (bx < 8192) {
        int i = bx * 256 + threadIdx.x;
        float4 v = ((const float4*)x)[i];
        unsigned long long r = (unsigned long long)f2bf(v.x)
                             | ((unsigned long long)f2bf(v.y) << 16)
                             | ((unsigned long long)f2bf(v.z) << 32)
                             | ((unsigned long long)f2bf(v.w) << 48);
        ((unsigned long long*)xb)[i] = r;
        return;
    }
    const float* in; ushort_t* out; int R, C, bidx;
    if (bx < 8192 + 3072) { in = wqkv; out = wqkvT; R = 1024; C = 3072; bidx = bx - 8192; }
    else                  { in = wproj; out = wprojT; R = 1024; C = 1024; bidx = bx - 11264; }
    int nbc = C >> 5;
    int bc = bidx % nbc, br = bidx / nbc;
    int tx = threadIdx.x & 31, ty = threadIdx.x >> 5;   // 32 x 8
    int r0 = br << 5, c0 = bc << 5;
#pragma unroll
    for (int j = 0; j < 4; ++j)
        t[ty + j * 8][tx] = in[(size_t)(r0 + ty + j * 8) * C + c0 + tx];
    __syncthreads();
#pragma unroll
    for (int j = 0; j < 4; ++j)
        out[(size_t)(c0 + ty + j * 8) * R + r0 + tx] = f2bf(t[tx][ty + j * 8]);
}

// ---------------- QKV GEMM: 128x384 tile, BK=64, counted-vmcnt, 16 waves, zero tail -------
// R13: K-tile schedule restructured 3 phases x 8 MFMA (6 barriers) -> 2 phases x 12 MFMA
// (4 barriers), split by k-slice: phase = {7 ds_reads (a x4 + b x3, one 32-wide k-slice) ->
// barrier -> lgkm(0) -> setprio -> 12 MFMA -> setprio -> barrier}. Staging + vmcnt(4) in
// phase 1 after all 14 reads issued — same hazard pattern as before (stage only after all
// reads of the buffer are issued). Per-element accumulation order unchanged (ks0 then ks1).
__global__ __launch_bounds__(1024) void gemm_qkv_kernel(const ushort_t* __restrict__ A,
                                                        const ushort_t* __restrict__ Bt,
                                                        const float* __restrict__ bias,
                                                        ushort_t* __restrict__ qbuf,
                                                        ushort_t* __restrict__ kbuf,
                                                        ushort_t* __restrict__ vtbuf) {
    extern __shared__ __align__(16) ushort_t lds[];

    int bid = blockIdx.x;
    int wg = (bid & 7) * 64 + (bid >> 3);      // XCD-bijective swizzle (512 % 8 == 0)
    int bm = wg & 63, bn = wg >> 6;            // 64 x 8
    int m0 = bm << 7, n0 = bn * 384;

    int tid = threadIdx.x;
    int wave = tid >> 6, lane = tid & 63;
    int c = lane & 15, g = lane >> 4;
    int wm = wave >> 3, wn = wave & 7;

    int row0 = tid >> 3;
    int sch  = (tid & 7) ^ (row0 & 7);
    size_t aoff = (size_t)(m0 + row0) * 1024 + sch * 8;
    size_t boff = (size_t)(n0 + row0) * 1024 + sch * 8;

    int co0 = (g * 8) ^ ((c & 7) << 3);

    floatx4 acc[4][3];
    short8 av[4], bv[3];
#pragma unroll
    for (int i2 = 0; i2 < 4; ++i2)
#pragma unroll
        for (int j2 = 0; j2 < 3; ++j2) { floatx4 z = {0.f,0.f,0.f,0.f}; acc[i2][j2] = z; }

    auto stA = [&](int t, int buf) {
        async_ld16(A + aoff + (size_t)t * 64, lds + buf * 8192 + tid * 8);
    };
    auto stB = [&](int t, int buf) {
        const ushort_t* s = Bt + boff + (size_t)t * 64;
        ushort_t* d = lds + 16384 + buf * 24576 + tid * 8;
        async_ld16(s, d);
        async_ld16(s + 131072, d + 8192);
        async_ld16(s + 262144, d + 16384);
    };
    auto ld_ks = [&](int buf, int ks) {
        int off = co0 ^ (ks << 5);             // co0 / co0^32
#pragma unroll
        for (int mi = 0; mi < 4; ++mi) {
            int ro = buf * 8192 + (wm * 64 + mi * 16 + c) * 64;
            av[mi] = *(const short8*)&lds[ro + off];
        }
#pragma unroll
        for (int nii = 0; nii < 3; ++nii) {
            int ro = 16384 + buf * 24576 + (wn * 48 + nii * 16 + c) * 64;
            bv[nii] = *(const short8*)&lds[ro + off];
        }
    };
    auto mm12 = [&]() {
        asm volatile("s_barrier" ::: "memory");
        asm volatile("s_waitcnt lgkmcnt(0)" ::: "memory");
        __builtin_amdgcn_s_setprio(1);
#pragma unroll
        for (int mi = 0; mi < 4; ++mi)
#pragma unroll
            for (int nii = 0; nii < 3; ++nii)
                acc[mi][nii] = __builtin_amdgcn_mfma_f32_16x16x32_bf16(
                    av[mi], bv[nii], acc[mi][nii], 0, 0, 0);
        __builtin_amdgcn_s_setprio(0);
        asm volatile("s_barrier" ::: "memory");
    };

    stA(0, 0); stB(0, 0);
    stA(1, 1); stB(1, 1);
    asm volatile("s_waitcnt vmcnt(4)" ::: "memory");
    asm volatile("s_barrier" ::: "memory");

#pragma unroll 1
    for (int t = 0; t < 14; ++t) {
        int buf = t & 1;
        ld_ks(buf, 0);
        mm12();
        ld_ks(buf, 1);
        stA(t + 2, buf); stB(t + 2, buf);      // all 14 reads of buf issued above
        asm volatile("s_waitcnt vmcnt(4)" ::: "memory");   // tile t+1 complete
        mm12();
    }
    // ---- tile 14 (buf 0) ----
    ld_ks(0, 0);
    mm12();
    ld_ks(0, 1);
    asm volatile("s_waitcnt vmcnt(0)" ::: "memory");       // tile 15 complete
    mm12();
    // ---- tile 15 (buf 1) ----
    ld_ks(1, 0);
    mm12();
    ld_ks(1, 1);
    mm12();

    int b = m0 >> 11, sbase = m0 & 2047;
    float bv_[3], scl[3];
    int headf[3], cinh[3], secf[3];
#pragma unroll
    for (int nii = 0; nii < 3; ++nii) {
        int cb = wn * 48 + nii * 16;
        bv_[nii]  = bias[n0 + cb + c];
        headf[nii] = cb >> 6;
        cinh[nii]  = (cb & 63) + c;
        secf[nii]  = (n0 + cb) >> 10;
        scl[nii]   = (secf[nii] == 0) ? (0.125f * LOG2E) : 1.0f;
    }

    __syncthreads();

#pragma unroll
    for (int nii = 0; nii < 3; ++nii) {
        if (secf[nii] < 2) {
#pragma unroll
            for (int mi = 0; mi < 4; ++mi)
#pragma unroll
                for (int r = 0; r < 4; ++r) {
                    int row = wm * 64 + mi * 16 + g * 4 + r;
                    lds[headf[nii] * 9216 + row * 72 + cinh[nii]] =
                        f2bf((acc[mi][nii][r] + bv_[nii]) * scl[nii]);
                }
        } else {
#pragma unroll
            for (int mi = 0; mi < 4; ++mi) {
                int d = cinh[nii];
                int s0 = wm * 64 + mi * 16 + g * 4;
                unsigned long long pk =
                      (unsigned long long)f2bf(acc[mi][nii][0] + bv_[nii])
                    | ((unsigned long long)f2bf(acc[mi][nii][1] + bv_[nii]) << 16)
                    | ((unsigned long long)f2bf(acc[mi][nii][2] + bv_[nii]) << 32)
                    | ((unsigned long long)f2bf(acc[mi][nii][3] + bv_[nii]) << 48);
                *(unsigned long long*)&lds[headf[nii] * 9216 + d * 136 + s0] = pk;
            }
        }
    }
    __syncthreads();

#pragma unroll 1
    for (int hl = 0; hl < 6; ++hl) {
        int colg = n0 + hl * 64;
        int sech = colg >> 10;
        int hg = (colg & 1023) >> 6;
        size_t bh = (size_t)(b * 16 + hg);
        if (sech < 2) {
            int row = tid >> 3, ch = tid & 7;
            ushort_t* dst = (sech == 0 ? qbuf : kbuf) + bh * 131072
                          + (size_t)(sbase + row) * 64 + ch * 8;
            *(short8*)dst = *(const short8*)&lds[hl * 9216 + row * 72 + ch * 8];
        } else {
            int d = tid >> 4, sq = tid & 15;
            ushort_t* dst = vtbuf + bh * 131072 + (size_t)d * 2048 + sbase + sq * 8;
            *(short8*)dst = *(const short8*)&lds[hl * 9216 + d * 136 + sq * 8];
        }
    }
}

// ---------------- flash attention: 32x32 MFMA, in-register softmax, kp-split waves --------
// FROZEN R6/R12 configuration (74 µs measured): separate Lo/Ll LDS (34.3 KB), (256,4),
// lacc ones-MFMA row-sum, exp2f, LPT 2048 blocks. R7-R11 showed every perturbation of this
// kernel's occupancy/LDS/register envelope loses 100+ µs. Do not touch.
__global__ __launch_bounds__(256, 4) void attn_kernel(const ushort_t* __restrict__ qb_,
                                                      const ushort_t* __restrict__ kb_,
                                                      const ushort_t* __restrict__ vtb_,
                                                      ushort_t* __restrict__ aout) {
    __shared__ __align__(16) ushort_t Ks[64 * 68];       // [kp][d] stride 68
    __shared__ __align__(16) ushort_t Vs[64 * 68];       // [d][kp] stride 68
    __shared__ __align__(16) float Lo[2][32][64];        // kh=1 partial O
    __shared__ float Ll[2][32];                          // kh=1 partial row-sum
    int bx = blockIdx.x;
    int qb = 31 - (bx >> 6);          // LPT: longest blocks dispatch first
    int bhix = bx & 63;
    int b = bhix >> 4, h = bhix & 15;
    int q0 = qb << 6;
    int tid = threadIdx.x, wave = tid >> 6, lane = tid & 63;
    int qh = wave >> 1, kh = wave & 1;
    int l31 = lane & 31, hi = lane >> 5;
    size_t bh = (size_t)(b * 16 + h);

    const ushort_t* Qp = qb_ + (bh * 2048 + q0 + qh * 32 + l31) * 64;
    const ushort_t* Kp = kb_ + bh * 131072;
    const ushort_t* Vp = vtb_ + bh * 131072;

    // Q as B-operand: col=l31 (q row), k elements d = s*16 + hi*8 + j
    short8 qf[4];
#pragma unroll
    for (int s = 0; s < 4; ++s)
        qf[s] = *(const short8*)(Qp + s * 16 + hi * 8);

    short8 vones;
#pragma unroll
    for (int j = 0; j < 8; ++j) vones[j] = (short)0x3F80;   // bf16 1.0

    floatx16 o0, o1, lacc;
#pragma unroll
    for (int i = 0; i < 16; ++i) { o0[i] = 0.f; o1[i] = 0.f; lacc[i] = 0.f; }

    short8 kreg[2], vreg[2];
#pragma unroll
    for (int it = 0; it < 2; ++it) {
        int idx = it * 256 + tid;
        kreg[it] = *(const short8*)(Kp + idx * 8);
        vreg[it] = *(const short8*)(Vp + (idx >> 3) * 2048 + (idx & 7) * 8);
    }

    int qg = q0 + qh * 32 + l31;
    int krow = (kh * 32 + l31) * 68 + hi * 8;
    for (int kt = 0; kt <= qb; ++kt) {
        int kt0 = kt << 6;
        __syncthreads();
#pragma unroll
        for (int it = 0; it < 2; ++it) {
            int idx = it * 256 + tid;
            *(short8*)&Ks[(idx >> 3) * 68 + (idx & 7) * 8] = kreg[it];
            *(short8*)&Vs[(idx >> 3) * 68 + (idx & 7) * 8] = vreg[it];
        }
        __syncthreads();
        if (kt < qb) {
            int s0 = (kt + 1) << 6;
#pragma unroll
            for (int it = 0; it < 2; ++it) {
                int idx = it * 256 + tid;
                kreg[it] = *(const short8*)(Kp + s0 * 64 + idx * 8);
                vreg[it] = *(const short8*)(Vp + (idx >> 3) * 2048 + s0 + (idx & 7) * 8);
            }
        }
        bool diag = (kt == qb);

        // QK^T: z[kp32][q32], A = K rows (this wave's kp-half), B = Q
        floatx16 z;
#pragma unroll
        for (int i = 0; i < 16; ++i) z[i] = 0.f;
#pragma unroll
        for (int s = 0; s < 4; ++s) {
            short8 kf = *(const short8*)&Ks[krow + s * 16];
            z = __builtin_amdgcn_mfma_f32_32x32x16_bf16(kf, qf[s], z, 0, 0, 0);
        }

        // mask + exp in place: z[r] -> P, kp = kt0 + kh*32 + (r&3)+8*(r>>2)+4*hi, q col = qg
        int kpb_ = kt0 + kh * 32 + 4 * hi;
#pragma unroll
        for (int r = 0; r < 16; ++r) {
            float s = z[r];
            if (diag) s = (kpb_ + (r & 3) + 8 * (r >> 2) > qg) ? -1e30f : s;
            z[r] = exp2f(s);
        }
        // pack to bf16 words: w[t][u2] = P pair at kp = 2*u2 + 8*t + 4*hi
        unsigned w[4][2];
#pragma unroll
        for (int t2 = 0; t2 < 4; ++t2)
#pragma unroll
            for (int u2 = 0; u2 < 2; ++u2) {
                union { unsigned u; __hip_bfloat162 h2; } pk;
                pk.h2 = __float22bfloat162_rn(
                    make_float2(z[t2 * 4 + u2 * 2], z[t2 * 4 + u2 * 2 + 1]));
                w[t2][u2] = pk.u;
            }
        // PV + row-sum: per k-step s (kp base s*16), assemble A-frag via half exchange
#pragma unroll
        for (int s = 0; s < 2; ++s) {
            unsigned s0w = hi ? w[2 * s][0] : w[2 * s + 1][0];
            unsigned s1w = hi ? w[2 * s][1] : w[2 * s + 1][1];
            unsigned r0 = (unsigned)__shfl_xor((int)s0w, 32);
            unsigned r1 = (unsigned)__shfl_xor((int)s1w, 32);
            union { unsigned u[4]; short8 v; } pa;
            if (hi == 0) { pa.u[0] = w[2*s][0]; pa.u[1] = w[2*s][1]; pa.u[2] = r0; pa.u[3] = r1; }
            else         { pa.u[0] = r0; pa.u[1] = r1; pa.u[2] = w[2*s+1][0]; pa.u[3] = w[2*s+1][1]; }
            short8 vb0 = *(const short8*)&Vs[l31 * 68 + kh * 32 + s * 16 + hi * 8];
            short8 vb1 = *(const short8*)&Vs[(32 + l31) * 68 + kh * 32 + s * 16 + hi * 8];
            o0   = __builtin_amdgcn_mfma_f32_32x32x16_bf16(pa.v, vb0,   o0,   0, 0, 0);
            o1   = __builtin_amdgcn_mfma_f32_32x32x16_bf16(pa.v, vb1,   o1,   0, 0, 0);
            lacc = __builtin_amdgcn_mfma_f32_32x32x16_bf16(pa.v, vones, lacc, 0, 0, 0);
        }
    }

    // cross-kp-half reduction: kh=1 writes partials, kh=0 adds, normalizes, stores.
    if (kh == 1) {
#pragma unroll
        for (int r = 0; r < 16; ++r) {
            int q = (r & 3) + 8 * (r >> 2) + 4 * hi;
            Lo[qh][q][l31]      = o0[r];
            Lo[qh][q][32 + l31] = o1[r];
        }
        if (l31 == 0) {
#pragma unroll
            for (int r = 0; r < 16; ++r)
                Ll[qh][(r & 3) + 8 * (r >> 2) + 4 * hi] = lacc[r];
        }
    }
    __syncthreads();
    if (kh == 0) {
#pragma unroll
        for (int r = 0; r < 16; ++r) {
            int q = (r & 3) + 8 * (r >> 2) + 4 * hi;
            float linv = 1.0f / (lacc[r] + Ll[qh][q]);
            int qgl = q0 + qh * 32 + q;
            size_t base = (size_t)(b * 2048 + qgl) * 1024 + h * 64;
            aout[base + l31]      = f2bf((o0[r] + Lo[qh][q][l31]) * linv);
            aout[base + 32 + l31] = f2bf((o1[r] + Lo[qh][q][32 + l31]) * linv);
        }
    }
}

// ---------------- proj GEMM: 256x128 tile, BK=64, counted-vmcnt, 16 waves, zero tail ------
// (unchanged)
__global__ __launch_bounds__(1024) void gemm_proj_kernel(const ushort_t* __restrict__ A,
                                                         const ushort_t* __restrict__ Bt,
                                                         const float* __restrict__ bias,
                                                         float* __restrict__ Cout) {
    extern __shared__ __align__(16) ushort_t lds[];

    int bid = blockIdx.x;
    int wg = (bid & 7) * 32 + (bid >> 3);      // XCD-bijective swizzle (256 % 8 == 0)
    int bm = wg & 31, bn = wg >> 5;
    int m0 = bm << 8, n0 = bn << 7;

    int tid = threadIdx.x;
    int wave = tid >> 6, lane = tid & 63;
    int c = lane & 15, g = lane >> 4;
    int wm = wave >> 2, wn = wave & 3;

    int row0 = tid >> 3;
    int sch  = (tid & 7) ^ (row0 & 7);
    size_t aoff = (size_t)(m0 + row0) * 1024 + sch * 8;
    size_t boff = (size_t)(n0 + row0) * 1024 + sch * 8;

    int co0 = (g * 8) ^ ((c & 7) << 3);
    int co1 = co0 ^ 32;

    floatx4 acc[4][2];
    short8 a[4][2], bb[2];
#pragma unroll
    for (int i2 = 0; i2 < 4; ++i2)
#pragma unroll
        for (int j2 = 0; j2 < 2; ++j2) { floatx4 z = {0.f,0.f,0.f,0.f}; acc[i2][j2] = z; }

    auto stA = [&](int t, int buf) {
        const ushort_t* s = A + aoff + (size_t)t * 64;
        ushort_t* d = lds + buf * 16384 + tid * 8;
        async_ld16(s, d);
        async_ld16(s + 131072, d + 8192);
    };
    auto stB = [&](int t, int buf) {
        async_ld16(Bt + boff + (size_t)t * 64, lds + 32768 + buf * 8192 + tid * 8);
    };
    auto ld_a = [&](int buf) {
#pragma unroll
        for (int mi = 0; mi < 4; ++mi) {
            int ro = buf * 16384 + (wm * 64 + mi * 16 + c) * 64;
            a[mi][0] = *(const short8*)&lds[ro + co0];
            a[mi][1] = *(const short8*)&lds[ro + co1];
        }
    };
    auto ld_b = [&](int buf, int nii) {
        int ro = 32768 + buf * 8192 + (wn * 32 + nii * 16 + c) * 64;
        bb[0] = *(const short8*)&lds[ro + co0];
        bb[1] = *(const short8*)&lds[ro + co1];
    };
    auto mm = [&](int nii) {
        asm volatile("s_barrier" ::: "memory");
        asm volatile("s_waitcnt lgkmcnt(0)" ::: "memory");
        __builtin_amdgcn_s_setprio(1);
#pragma unroll
        for (int mi = 0; mi < 4; ++mi)
#pragma unroll
            for (int ks = 0; ks < 2; ++ks)
                acc[mi][nii] = __builtin_amdgcn_mfma_f32_16x16x32_bf16(
                    a[mi][ks], bb[ks], acc[mi][nii], 0, 0, 0);
        __builtin_amdgcn_s_setprio(0);
        asm volatile("s_barrier" ::: "memory");
    };

    stA(0, 0); stB(0, 0);
    stA(1, 1); stB(1, 1);
    asm volatile("s_waitcnt vmcnt(3)" ::: "memory");
    asm volatile("s_barrier" ::: "memory");

#pragma unroll 1
    for (int t = 0; t < 14; ++t) {
        int buf = t & 1;
        ld_a(buf); ld_b(buf, 0);
        mm(0);
        ld_b(buf, 1);
        stA(t + 2, buf); stB(t + 2, buf);
        asm volatile("s_waitcnt vmcnt(3)" ::: "memory");
        mm(1);
    }
    ld_a(0); ld_b(0, 0);
    mm(0);
    ld_b(0, 1);
    asm volatile("s_waitcnt vmcnt(0)" ::: "memory");
    mm(1);
    ld_a(1); ld_b(1, 0);
    mm(0);
    ld_b(1, 1);
    mm(1);

    float bv[2];
#pragma unroll
    for (int nii = 0; nii < 2; ++nii) bv[nii] = bias[n0 + wn * 32 + nii * 16 + c];
#pragma unroll
    for (int mi = 0; mi < 4; ++mi)
#pragma unroll
        for (int nii = 0; nii < 2; ++nii)
#pragma unroll
            for (int r = 0; r < 4; ++r) {
                int row = m0 + wm * 64 + mi * 16 + g * 4 + r;
                int col = n0 + wn * 32 + nii * 16 + c;
                Cout[(size_t)row * 1024 + col] = acc[mi][nii][r] + bv[nii];
            }
}

extern "C" void kernel_launch(void* const* d_in, const int* in_sizes, int n_in,
                              void* d_out, int out_size, void* d_ws, size_t ws_size,
                              hipStream_t stream) {
    const float* x        = (const float*)d_in[0];
    const float* c_attn_w = (const float*)d_in[1];
    const float* c_attn_b = (const float*)d_in[2];
    const float* c_proj_w = (const float*)d_in[3];
    const float* c_proj_b = (const float*)d_in[4];
    float* out = (float*)d_out;

    char* ws = (char*)d_ws;
    ushort_t* xb     = (ushort_t*)(ws);              // 16 MB; reused as attn output 'a'
    ushort_t* wqkvT  = (ushort_t*)(ws + 16777216);   // 6 MB
    ushort_t* wprojT = (ushort_t*)(ws + 23068672);   // 2 MB
    ushort_t* qbuf   = (ushort_t*)(ws + 25165824);   // 16 MB  [bh][s][64]  (pre-scaled)
    ushort_t* kbuf   = (ushort_t*)(ws + 41943040);   // 16 MB  [bh][s][64]
    ushort_t* vtbuf  = (ushort_t*)(ws + 58720256);   // 16 MB  [bh][64][2048]

    static bool s_attr_set = false;
    if (!s_attr_set) {
        (void)hipFuncSetAttribute(reinterpret_cast<const void*>(gemm_qkv_kernel),
                                  hipFuncAttributeMaxDynamicSharedMemorySize, 131072);
        (void)hipFuncSetAttribute(reinterpret_cast<const void*>(gemm_proj_kernel),
                                  hipFuncAttributeMaxDynamicSharedMemorySize, 98304);
        s_attr_set = true;
    }

    prep_kernel<<<12288, 256, 0, stream>>>(x, c_attn_w, c_proj_w, xb, wqkvT, wprojT);
    gemm_qkv_kernel<<<512, 1024, 131072, stream>>>(xb, wqkvT, c_attn_b, qbuf, kbuf, vtbuf);
    attn_kernel<<<2048, 256, 0, stream>>>(qbuf, kbuf, vtbuf, xb);
    gemm_proj_kernel<<<256, 1024, 98304, stream>>>(xb, wprojT, c_proj_b, out);
}